// Round 1
// baseline (169.637 us; speedup 1.0000x reference)
//
#include <hip/hip_runtime.h>
#include <hip/hip_bf16.h>

#define N_NODES 51
#define F_IN 4
#define P_DIM 137
#define EMB 32
#define E_EDGES 408
#define B_DIM 32
#define PC 5            // periods per block chunk
#define NCHUNK 28       // ceil(137/5)
#define NE (N_NODES*EMB)   // 1632
#define NF (N_NODES*F_IN)  // 204

__global__ void zero_kernel(float* __restrict__ p, int n) {
    int i = blockIdx.x * blockDim.x + threadIdx.x;
    if (i < n) p[i] = 0.0f;
}

// One block. Builds dense normalized adjacency Ahat[51][51] (with self loops,
// D^-1/2 (A+I) D^-1/2, directed src->dst) and softmax(attention).
__global__ __launch_bounds__(256) void precompute_kernel(
    const int* __restrict__ edge_index, const float* __restrict__ attention,
    float* __restrict__ Amat_g, float* __restrict__ probs_g)
{
    __shared__ float deg[N_NODES];
    __shared__ float dinv[N_NODES];
    __shared__ float Am[N_NODES * N_NODES];
    __shared__ float att[P_DIM];
    __shared__ float inv_sum;
    int t = threadIdx.x;
    for (int i = t; i < N_NODES * N_NODES; i += 256) Am[i] = 0.0f;
    if (t < N_NODES) deg[t] = 0.0f;
    __syncthreads();
    for (int e = t; e < E_EDGES; e += 256) {
        int d = edge_index[E_EDGES + e];
        atomicAdd(&deg[d], 1.0f);
    }
    __syncthreads();
    if (t < N_NODES) {  // self loop adds 1 to every node's in-degree
        float dg = deg[t] + 1.0f;
        dinv[t] = rsqrtf(dg);   // dg >= 1 always
    }
    __syncthreads();
    for (int e = t; e < E_EDGES; e += 256) {
        int s = edge_index[e];
        int d = edge_index[E_EDGES + e];
        atomicAdd(&Am[d * N_NODES + s], dinv[s] * dinv[d]);
    }
    __syncthreads();
    if (t < N_NODES) Am[t * N_NODES + t] += dinv[t] * dinv[t];
    if (t < P_DIM) att[t] = attention[t];
    __syncthreads();
    for (int i = t; i < N_NODES * N_NODES; i += 256) Amat_g[i] = Am[i];
    if (t == 0) {
        float m = -1e30f;
        for (int p = 0; p < P_DIM; p++) m = fmaxf(m, att[p]);
        float s = 0.0f;
        for (int p = 0; p < P_DIM; p++) { float v = __expf(att[p] - m); att[p] = v; s += v; }
        inv_sum = 1.0f / s;
    }
    __syncthreads();
    if (t < P_DIM) probs_g[t] = att[t] * inv_sum;
}

// grid (NCHUNK, B). Each block: one batch element, PC consecutive periods.
// Per period: load x slice -> Ahat aggregation (F=4) -> two 4->32 convs ->
// two 32->32 gate matmuls + sigmoid/tanh -> probs-weighted accumulate in LDS.
// End: one global atomicAdd per (n,e) element.
__global__ __launch_bounds__(256) void main_kernel(
    const float* __restrict__ x, const float* __restrict__ Amat,
    const float* __restrict__ Wz, const float* __restrict__ bz,
    const float* __restrict__ Wh, const float* __restrict__ bh,
    const float* __restrict__ Uz, const float* __restrict__ bz2,
    const float* __restrict__ Uh, const float* __restrict__ bh2,
    const float* __restrict__ probs, float* __restrict__ h_out)
{
    __shared__ float Am[N_NODES * N_NODES];   // 2601
    __shared__ float Uzs[EMB * EMB];          // first 32 rows of lin_z_w (H=0 => rest dead)
    __shared__ float Uhs[EMB * EMB];
    __shared__ float Wzs[F_IN * EMB];
    __shared__ float Whs[F_IN * EMB];
    __shared__ float bzs[EMB], bhs[EMB], bz2s[EMB], bh2s[EMB];
    __shared__ float xs[NF];
    __shared__ float agg[NF];
    __shared__ float czs[NE];
    __shared__ float chs[NE];
    __shared__ float hl[NE];

    int t = threadIdx.x;
    int b = blockIdx.y;
    int p0 = blockIdx.x * PC;
    int p1 = min(p0 + PC, P_DIM);

    for (int i = t; i < N_NODES * N_NODES; i += 256) Am[i] = Amat[i];
    for (int i = t; i < EMB * EMB; i += 256) { Uzs[i] = Uz[i]; Uhs[i] = Uh[i]; }
    if (t < F_IN * EMB) { Wzs[t] = Wz[t]; Whs[t] = Wh[t]; }
    if (t < EMB) { bzs[t] = bz[t]; bhs[t] = bh[t]; bz2s[t] = bz2[t]; bh2s[t] = bh2[t]; }
    for (int i = t; i < NE; i += 256) hl[i] = 0.0f;
    __syncthreads();

    for (int p = p0; p < p1; p++) {
        float pr = probs[p];
        if (t < NF) {
            int n = t >> 2, f = t & 3;
            xs[t] = x[(((b * N_NODES) + n) * F_IN + f) * P_DIM + p];
        }
        __syncthreads();
        if (t < NF) {   // agg[d][f] = sum_s Ahat[d][s] * x[s][f]
            int d = t >> 2, f = t & 3;
            const float* Ar = &Am[d * N_NODES];
            float a = 0.0f;
            for (int s = 0; s < N_NODES; s++) a += Ar[s] * xs[s * F_IN + f];
            agg[t] = a;
        }
        __syncthreads();
        for (int i = t; i < NE; i += 256) {   // 4->32 convs
            int d = i >> 5, e = i & 31;
            float az = bzs[e], ah = bhs[e];
            #pragma unroll
            for (int f = 0; f < F_IN; f++) {
                float av = agg[d * F_IN + f];
                az += av * Wzs[f * EMB + e];
                ah += av * Whs[f * EMB + e];
            }
            czs[i] = az; chs[i] = ah;
        }
        __syncthreads();
        for (int i = t; i < NE; i += 256) {   // gates: Z=sigmoid, Ht=tanh, acc (1-Z)*Ht
            int d = i >> 5, e = i & 31;
            float az = bz2s[e], ah = bh2s[e];
            const float* cr = &czs[d * EMB];
            const float* hr = &chs[d * EMB];
            #pragma unroll
            for (int k = 0; k < EMB; k++) {
                az += cr[k] * Uzs[k * EMB + e];
                ah += hr[k] * Uhs[k * EMB + e];
            }
            float Z  = 1.0f / (1.0f + __expf(-az));            // safe at extremes
            float Ht = 2.0f / (1.0f + __expf(-2.0f * ah)) - 1.0f; // tanh, safe at extremes
            hl[i] += pr * (1.0f - Z) * Ht;
        }
        __syncthreads();
    }
    for (int i = t; i < NE; i += 256) atomicAdd(&h_out[b * NE + i], hl[i]);
}

// grid (B). out[b] = sigmoid( sum_{n,e} w3[n]*w2[e]*relu(lin1(relu(h))[n,e])
//                             + b2*sum_n w3[n] + b3 )
__global__ __launch_bounds__(256) void head_kernel(
    const float* __restrict__ h, const float* __restrict__ W1,
    const float* __restrict__ b1, const float* __restrict__ w2,
    const float* __restrict__ b2, const float* __restrict__ w3,
    const float* __restrict__ b3, float* __restrict__ out)
{
    __shared__ float hs[NE];
    __shared__ float W1s[EMB * EMB];
    __shared__ float b1s[EMB], w2s[EMB];
    __shared__ float w3s[N_NODES];
    __shared__ float wsum[4];
    int t = threadIdx.x, b = blockIdx.x;
    for (int i = t; i < NE; i += 256) hs[i] = fmaxf(h[b * NE + i], 0.0f);
    for (int i = t; i < EMB * EMB; i += 256) W1s[i] = W1[i];
    if (t < EMB) { b1s[t] = b1[t]; w2s[t] = w2[t]; }
    if (t < N_NODES) w3s[t] = w3[t];
    __syncthreads();
    float acc = 0.0f;
    for (int i = t; i < NE; i += 256) {
        int d = i >> 5, e = i & 31;
        float a = b1s[e];
        const float* hr = &hs[d * EMB];
        #pragma unroll
        for (int k = 0; k < EMB; k++) a += hr[k] * W1s[k * EMB + e];
        a = fmaxf(a, 0.0f);
        acc += w3s[d] * w2s[e] * a;
    }
    #pragma unroll
    for (int off = 32; off > 0; off >>= 1) acc += __shfl_down(acc, off);
    if ((t & 63) == 0) wsum[t >> 6] = acc;
    __syncthreads();
    if (t == 0) {
        float s = wsum[0] + wsum[1] + wsum[2] + wsum[3];
        float s3 = 0.0f;
        for (int d = 0; d < N_NODES; d++) s3 += w3s[d];
        float v = s + b2[0] * s3 + b3[0];
        out[b] = 1.0f / (1.0f + __expf(-v));
    }
}

extern "C" void kernel_launch(void* const* d_in, const int* in_sizes, int n_in,
                              void* d_out, int out_size, void* d_ws, size_t ws_size,
                              hipStream_t stream) {
    const float* x         = (const float*)d_in[0];
    const int*   ei        = (const int*)d_in[1];
    const float* conv_z_w  = (const float*)d_in[2];
    const float* conv_z_b  = (const float*)d_in[3];
    // d_in[4], d_in[5]: conv_r_* — dead (H=0 kills the R gate)
    const float* conv_h_w  = (const float*)d_in[6];
    const float* conv_h_b  = (const float*)d_in[7];
    const float* lin_z_w   = (const float*)d_in[8];
    const float* lin_z_b   = (const float*)d_in[9];
    // d_in[10], d_in[11]: lin_r_* — dead
    const float* lin_h_w   = (const float*)d_in[12];
    const float* lin_h_b   = (const float*)d_in[13];
    const float* attention = (const float*)d_in[14];
    const float* lin1_w    = (const float*)d_in[15];
    const float* lin1_b    = (const float*)d_in[16];
    const float* lin2_w    = (const float*)d_in[17];
    const float* lin2_b    = (const float*)d_in[18];
    const float* lin3_w    = (const float*)d_in[19];
    const float* lin3_b    = (const float*)d_in[20];

    float* ws    = (float*)d_ws;
    float* Amat  = ws;          // 2601 floats
    float* probs = ws + 2624;   // 137 floats
    float* h     = ws + 2816;   // B*N*EMB = 52224 floats
    float* out   = (float*)d_out;

    hipLaunchKernelGGL(zero_kernel, dim3((B_DIM * NE + 255) / 256), dim3(256), 0, stream,
                       h, B_DIM * NE);
    hipLaunchKernelGGL(precompute_kernel, dim3(1), dim3(256), 0, stream,
                       ei, attention, Amat, probs);
    hipLaunchKernelGGL(main_kernel, dim3(NCHUNK, B_DIM), dim3(256), 0, stream,
                       x, Amat, conv_z_w, conv_z_b, conv_h_w, conv_h_b,
                       lin_z_w, lin_z_b, lin_h_w, lin_h_b, probs, h);
    hipLaunchKernelGGL(head_kernel, dim3(B_DIM), dim3(256), 0, stream,
                       h, lin1_w, lin1_b, lin2_w, lin2_b, lin3_w, lin3_b, out);
}